// Round 10
// baseline (68.081 us; speedup 1.0000x reference)
//
#include <hip/hip_runtime.h>

// VectorQuantizer: fp16-MFMA filter + exact fp32 rescore, 3 kernels.
// z_e [16,1024,256] f32, codebook [1024,256] f32
// out = concat( z_q [16,1024,256] f32 , indices [16,1024] as f32 )
//
// K1 vq_prep_cb: cb -> fp16 MFMA-fragment order + exact fp32 csq
// K2 vq_score: grid (256 rowTiles, 4 cg) x 256 thr (4 waves).
//    Stage 64 rows of z f32->fp16 fragments in LDS (32 KB). Wave wv scores
//    colTile cg*4+wv (64 codes) via 16x16x32 f16 MFMA, acc[4][4].
//    u32 keys (truncated score | idx), DPP 16-lane top-2, cross-wave LDS
//    merge -> cand[row][8] (top-2 per 256-code group).
//    NOTE: no __launch_bounds__ second arg — it clamps VGPR to 64 and spills
//    (measured R2/R7/R8); occupancy comes from block size + 34 KB LDS.
// K3 vq_final: wave per row; 8 cands in parallel (8 lanes each), exact fp32
//    dot + DPP reduce + u64 DPP min-merge; gather z_q, write idx.

#define M_ROWS 16384
#define DDIM   256
#define NCODES 1024

typedef _Float16 half8 __attribute__((ext_vector_type(8)));
typedef float    f32x4 __attribute__((ext_vector_type(4)));

__device__ __forceinline__ unsigned int f2ord(float f) {
    unsigned int u = __float_as_uint(f);
    return (u & 0x80000000u) ? ~u : (u | 0x80000000u);
}

#define DPP_SELF(k, ctrl) \
    ((unsigned)__builtin_amdgcn_update_dpp((int)(k), (int)(k), (ctrl), 0xF, 0xF, false))
#define DPP_Z(v, ctrl) \
    __builtin_amdgcn_update_dpp(0, (v), (ctrl), 0xF, 0xF, true)

// 64-lane sum via DPP; total valid in lane 63
__device__ __forceinline__ float dpp_radd(float x) {
    float s = x;
    s += __int_as_float(DPP_Z(__float_as_int(s), 0x111));
    s += __int_as_float(DPP_Z(__float_as_int(s), 0x112));
    s += __int_as_float(DPP_Z(__float_as_int(s), 0x114));
    s += __int_as_float(DPP_Z(__float_as_int(s), 0x118));
    s += __int_as_float(DPP_Z(__float_as_int(s), 0x142));
    s += __int_as_float(DPP_Z(__float_as_int(s), 0x143));
    return s;
}

// ---------------- K1: pack cb (blocks 0..127) + csq (blocks 128..383) ------
__global__ __launch_bounds__(256) void vq_prep_cb(const float* __restrict__ cb,
                                                  _Float16* __restrict__ chp,
                                                  float* __restrict__ csq) {
    if (blockIdx.x < 128) {
        const int gid = blockIdx.x * 256 + threadIdx.x;
        const int l   = gid & 63;
        const int g   = gid >> 6;
        const int kt  = g & 7;
        const int rt  = g >> 3;
        const int row = rt * 16 + (l & 15);
        const int k0  = kt * 32 + (l >> 4) * 8;
        const float4 v0 = *reinterpret_cast<const float4*>(cb + (size_t)row * DDIM + k0);
        const float4 v1 = *reinterpret_cast<const float4*>(cb + (size_t)row * DDIM + k0 + 4);
        half8 h;
        h[0] = (_Float16)v0.x; h[1] = (_Float16)v0.y; h[2] = (_Float16)v0.z; h[3] = (_Float16)v0.w;
        h[4] = (_Float16)v1.x; h[5] = (_Float16)v1.y; h[6] = (_Float16)v1.z; h[7] = (_Float16)v1.w;
        *reinterpret_cast<half8*>(chp + (size_t)gid * 8) = h;
    } else {
        const int code = (blockIdx.x - 128) * 4 + (threadIdx.x >> 6);
        const int lane = threadIdx.x & 63;
        const float4 v = *reinterpret_cast<const float4*>(cb + (size_t)code * DDIM + lane * 4);
        float s = v.x * v.x + v.y * v.y + v.z * v.z + v.w * v.w;
        s = dpp_radd(s);
        if (lane == 63) csq[code] = s;
    }
}

// ---------------- K2: approx scores + top-2 per 256 codes -> cand ----------
__global__ __launch_bounds__(256) void vq_score(const float* __restrict__ z,
                                                const _Float16* __restrict__ Bp,
                                                const float* __restrict__ csq,
                                                unsigned* __restrict__ cand) {
    __shared__ __align__(16) _Float16 Ah[64 * 256];   // 32 KB fragment-order
    __shared__ uint2 red[4][64];                      // 2 KB top-2 per wave/row

    const int tid  = threadIdx.x;
    const int lane = tid & 63;
    const int wv   = tid >> 6;            // 0..3
    const int rowBase = blockIdx.x * 64;
    const int cg      = blockIdx.y;       // 0..3

    // ---- P1: stage 64 rows x 256 dims as fp16 fragments (32 granules) ----
#pragma unroll
    for (int i = 0; i < 8; ++i) {
        const int slot = i * 256 + tid;   // 0..2047
        const int l  = slot & 63;
        const int g  = slot >> 6;         // 0..31 = m*8 + kt
        const int m  = g >> 3;
        const int kt = g & 7;
        const int row = rowBase + m * 16 + (l & 15);
        const int k0  = kt * 32 + (l >> 4) * 8;
        const float4 v0 = *reinterpret_cast<const float4*>(z + (size_t)row * DDIM + k0);
        const float4 v1 = *reinterpret_cast<const float4*>(z + (size_t)row * DDIM + k0 + 4);
        half8 h;
        h[0] = (_Float16)v0.x; h[1] = (_Float16)v0.y; h[2] = (_Float16)v0.z; h[3] = (_Float16)v0.w;
        h[4] = (_Float16)v1.x; h[5] = (_Float16)v1.y; h[6] = (_Float16)v1.z; h[7] = (_Float16)v1.w;
        *reinterpret_cast<half8*>(&Ah[g * 512 + l * 8]) = h;
    }
    __syncthreads();

    // ---- P2: MFMA scores for this wave's colTile (64 codes) ----
    const half8* __restrict__ B = reinterpret_cast<const half8*>(Bp);
    const int colTile = cg * 4 + wv;      // 0..15
    const int colBase = colTile * 64;
    const int cx = lane & 15;
    const int q  = lane >> 4;

    f32x4 acc[4][4];
#pragma unroll
    for (int m = 0; m < 4; ++m)
#pragma unroll
        for (int n = 0; n < 4; ++n) acc[m][n] = (f32x4){0.f, 0.f, 0.f, 0.f};

#pragma unroll
    for (int kt = 0; kt < 8; ++kt) {
        half8 a[4], b[4];
#pragma unroll
        for (int m = 0; m < 4; ++m)
            a[m] = *reinterpret_cast<const half8*>(&Ah[(m * 8 + kt) * 512 + lane * 8]);
#pragma unroll
        for (int n = 0; n < 4; ++n)
            b[n] = B[(size_t)(((colTile * 4 + n) * 8 + kt) * 64 + lane)];
#pragma unroll
        for (int m = 0; m < 4; ++m)
#pragma unroll
            for (int n = 0; n < 4; ++n)
                acc[m][n] = __builtin_amdgcn_mfma_f32_16x16x32_f16(a[m], b[n], acc[m][n], 0, 0, 0);
    }

    // ---- epilogue: transient u32-key top-2 per (m,r), DPP 16-lane merge ----
    float csv[4];
#pragma unroll
    for (int n = 0; n < 4; ++n) csv[n] = csq[colBase + n * 16 + cx];

#pragma unroll
    for (int m = 0; m < 4; ++m)
#pragma unroll
        for (int r = 0; r < 4; ++r) {
            unsigned k0 = 0xFFFFFFFFu, k1 = 0xFFFFFFFFu;
#pragma unroll
            for (int n = 0; n < 4; ++n) {
                const float s = fmaf(-2.0f, acc[m][n][r], csv[n]);
                const unsigned key = (f2ord(s) & 0xFFFFFC00u)
                                   | (unsigned)(colBase + n * 16 + cx);
                if (key < k0) { k1 = k0; k0 = key; }
                else if (key < k1) { k1 = key; }
            }
#define MERGE_STEP(CTRL)                                              \
            {                                                         \
                const unsigned o0 = DPP_SELF(k0, CTRL);               \
                const unsigned o1 = DPP_SELF(k1, CTRL);               \
                const unsigned lo = (k0 < o0) ? k0 : o0;              \
                const unsigned hi = (k0 < o0) ? o0 : k0;              \
                const unsigned m1 = (k1 < o1) ? k1 : o1;              \
                k1 = (hi < m1) ? hi : m1;                             \
                k0 = lo;                                              \
            }
            MERGE_STEP(0x111)
            MERGE_STEP(0x112)
            MERGE_STEP(0x114)
            MERGE_STEP(0x118)
#undef MERGE_STEP
            if (cx == 15) red[wv][m * 16 + q * 4 + r] = make_uint2(k0, k1);
        }
    __syncthreads();

    // ---- merge 4 waves -> top-2 per 256 codes -> cand[row][8] ----
    if (tid < 64) {
        unsigned b0 = 0xFFFFFFFFu, b1 = 0xFFFFFFFFu;
#pragma unroll
        for (int w = 0; w < 4; ++w) {
            const uint2 v = red[w][tid];
            if (v.x < b0) { b1 = b0; b0 = v.x; } else if (v.x < b1) { b1 = v.x; }
            if (v.y < b0) { b1 = b0; b0 = v.y; } else if (v.y < b1) { b1 = v.y; }
        }
        uint2 outv; outv.x = b0; outv.y = b1;
        *reinterpret_cast<uint2*>(&cand[((size_t)(rowBase + tid)) * 8 + cg * 2]) = outv;
    }
}

// ---------------- K3: exact fp32 rescore of 8 cands + gather ---------------
__global__ __launch_bounds__(256) void vq_final(const float* __restrict__ z,
                                                const float* __restrict__ cb,
                                                const float* __restrict__ csq,
                                                const unsigned* __restrict__ cand,
                                                float* __restrict__ zq,
                                                float* __restrict__ outIdx) {
    const int lane = threadIdx.x & 63;
    const int row  = blockIdx.x * 4 + (threadIdx.x >> 6);
    const int g    = lane >> 3;       // candidate 0..7
    const int jj   = lane & 7;        // dim slice within group

    const unsigned ck = cand[(size_t)row * 8 + g];
    const int idx = (int)(ck & 1023u);

    // exact fp32 partial dot over dims [jj*32, jj*32+32)
    const float* crow = cb + (size_t)idx * DDIM + jj * 32;
    const float* zrow = z  + (size_t)row * DDIM + jj * 32;
    float p = 0.0f;
#pragma unroll
    for (int t = 0; t < 8; ++t) {
        const float4 cv = *reinterpret_cast<const float4*>(crow + t * 4);
        const float4 zv = *reinterpret_cast<const float4*>(zrow + t * 4);
        p = fmaf(zv.x, cv.x, fmaf(zv.y, cv.y, fmaf(zv.z, cv.z, fmaf(zv.w, cv.w, p))));
    }
    // group-of-8 sum; leader lane (jj==7) holds the full dot
    p += __int_as_float(DPP_Z(__float_as_int(p), 0x111));
    p += __int_as_float(DPP_Z(__float_as_int(p), 0x112));
    p += __int_as_float(DPP_Z(__float_as_int(p), 0x114));

    // leaders form u64 key (score, idx); others worst
    unsigned kh, kl;
    if (jj == 7) {
        kh = f2ord(fmaf(-2.0f, p, csq[idx]));
        kl = (unsigned)idx;
    } else {
        kh = 0xFFFFFFFFu; kl = 0xFFFFFFFFu;
    }
    // u64 min-merge across the 8 leaders -> lane 63
#define MIN64_STEP(CTRL)                                              \
    {                                                                 \
        const unsigned oh = DPP_SELF(kh, CTRL);                       \
        const unsigned ol = DPP_SELF(kl, CTRL);                       \
        const bool tk = (oh < kh) || (oh == kh && ol < kl);           \
        kh = tk ? oh : kh;                                            \
        kl = tk ? ol : kl;                                            \
    }
    MIN64_STEP(0x118)   // row_shr:8
    MIN64_STEP(0x142)   // row_bcast:15
    MIN64_STEP(0x143)   // row_bcast:31
#undef MIN64_STEP
    const int bestI = __builtin_amdgcn_readlane((int)kl, 63);

    if (lane == 0) outIdx[row] = (float)bestI;
    const float4 q4 = *reinterpret_cast<const float4*>(cb + (size_t)bestI * DDIM + lane * 4);
    *reinterpret_cast<float4*>(zq + (size_t)row * DDIM + lane * 4) = q4;
}

extern "C" void kernel_launch(void* const* d_in, const int* in_sizes, int n_in,
                              void* d_out, int out_size, void* d_ws, size_t ws_size,
                              hipStream_t stream) {
    const float* z  = (const float*)d_in[0];   // [16384,256]
    const float* cb = (const float*)d_in[1];   // [1024,256]
    float* out    = (float*)d_out;
    float* zq     = out;                            // 16.77 MB
    float* outIdx = out + (size_t)M_ROWS * DDIM;    // 64 KB

    char* ws = (char*)d_ws;
    _Float16* chp  = (_Float16*)ws;                       // 512 KB
    float* csq     = (float*)(ws + 512 * 1024);           // 4 KB
    unsigned* cand = (unsigned*)(ws + 512 * 1024 + 4096); // 512 KB

    vq_prep_cb<<<384, 256, 0, stream>>>(cb, chp, csq);
    dim3 sg(M_ROWS / 64, 4);
    vq_score<<<sg, 256, 0, stream>>>(z, chp, csq, cand);
    vq_final<<<M_ROWS / 4, 256, 0, stream>>>(z, cb, csq, cand, zq, outIdx);
}

// Round 11
// 42.170 us; speedup vs baseline: 1.6144x; 1.6144x over previous
//
#include <hip/hip_runtime.h>

// VectorQuantizer: fp16-MFMA filter + exact fp32 rescore, 3 kernels.
// z_e [16,1024,256] f32, codebook [1024,256] f32
// out = concat( z_q [16,1024,256] f32 , indices [16,1024] as f32 )
//
// K1 vq_prep: blocks 0..2047 pack z->fp16 frags (into d_out scratch region),
//             2048..2175 pack cb->fp16 frags, 2176..2431 exact fp32 csq.
// K2 vq_score: grid (256 rowTiles, 4 cg) x 256 thr. R5-verbatim (measured
//    best): stage packed A (32 KB) to LDS, wave = one 64-code colTile,
//    16x16x32 f16 MFMA acc[4][4], u32 keys, DPP 16-lane top-2, cross-wave
//    LDS merge -> cand[row][8] (top-2 per 256-code group).
// K3 vq_final: wave per row. z read ONCE per lane; all 8 candidate cb rows
//    loaded up-front (ILP), 8 independent DPP reduce chains, argmin on
//    lane 63, z_q selected from the loaded registers (no re-gather).

#define M_ROWS 16384
#define DDIM   256
#define NCODES 1024

typedef _Float16 half8 __attribute__((ext_vector_type(8)));
typedef float    f32x4 __attribute__((ext_vector_type(4)));

__device__ __forceinline__ unsigned int f2ord(float f) {
    unsigned int u = __float_as_uint(f);
    return (u & 0x80000000u) ? ~u : (u | 0x80000000u);
}

#define DPP_SELF(k, ctrl) \
    ((unsigned)__builtin_amdgcn_update_dpp((int)(k), (int)(k), (ctrl), 0xF, 0xF, false))
#define DPP_Z(v, ctrl) \
    __builtin_amdgcn_update_dpp(0, (v), (ctrl), 0xF, 0xF, true)

// 64-lane sum via DPP; total valid in lane 63
__device__ __forceinline__ float dpp_radd(float x) {
    float s = x;
    s += __int_as_float(DPP_Z(__float_as_int(s), 0x111));
    s += __int_as_float(DPP_Z(__float_as_int(s), 0x112));
    s += __int_as_float(DPP_Z(__float_as_int(s), 0x114));
    s += __int_as_float(DPP_Z(__float_as_int(s), 0x118));
    s += __int_as_float(DPP_Z(__float_as_int(s), 0x142));
    s += __int_as_float(DPP_Z(__float_as_int(s), 0x143));
    return s;
}

__device__ __forceinline__ void pack_granule(const float* __restrict__ src,
                                             _Float16* __restrict__ dst, int gid) {
    const int l   = gid & 63;
    const int g   = gid >> 6;          // rt*8 + kt
    const int kt  = g & 7;
    const int rt  = g >> 3;
    const int row = rt * 16 + (l & 15);
    const int k0  = kt * 32 + (l >> 4) * 8;
    const float4 v0 = *reinterpret_cast<const float4*>(src + (size_t)row * DDIM + k0);
    const float4 v1 = *reinterpret_cast<const float4*>(src + (size_t)row * DDIM + k0 + 4);
    half8 h;
    h[0] = (_Float16)v0.x; h[1] = (_Float16)v0.y; h[2] = (_Float16)v0.z; h[3] = (_Float16)v0.w;
    h[4] = (_Float16)v1.x; h[5] = (_Float16)v1.y; h[6] = (_Float16)v1.z; h[7] = (_Float16)v1.w;
    *reinterpret_cast<half8*>(dst + (size_t)gid * 8) = h;
}

// ---------------- K1: pack z + pack cb + csq ----------------
__global__ __launch_bounds__(256) void vq_prep(const float* __restrict__ z,
                                               const float* __restrict__ cb,
                                               _Float16* __restrict__ zhp,
                                               _Float16* __restrict__ chp,
                                               float* __restrict__ csq) {
    const int b = blockIdx.x;
    if (b < 2048) {
        pack_granule(z, zhp, b * 256 + threadIdx.x);
    } else if (b < 2176) {
        pack_granule(cb, chp, (b - 2048) * 256 + threadIdx.x);
    } else {
        const int code = (b - 2176) * 4 + (threadIdx.x >> 6);
        const int lane = threadIdx.x & 63;
        const float4 v = *reinterpret_cast<const float4*>(cb + (size_t)code * DDIM + lane * 4);
        float s = v.x * v.x + v.y * v.y + v.z * v.z + v.w * v.w;
        s = dpp_radd(s);
        if (lane == 63) csq[code] = s;
    }
}

// ---------------- K2: approx scores + top-2 per 256 codes (R5 verbatim) ----
__global__ __launch_bounds__(256, 4) void vq_score(const _Float16* __restrict__ Ap,
                                                   const _Float16* __restrict__ Bp,
                                                   const float* __restrict__ csq,
                                                   unsigned* __restrict__ cand) {
    __shared__ __align__(16) _Float16 As[64 * 256];   // 32 KB, fragment-linear
    __shared__ uint2 red[4][64];

    const int tid  = threadIdx.x;
    const int lane = tid & 63;
    const int wv   = tid >> 6;
    const int rowTile = blockIdx.x;
    const int cg      = blockIdx.y;

    // stage A tile (32 KB contiguous in packed layout)
    {
        const uint4* src = reinterpret_cast<const uint4*>(Ap + (size_t)rowTile * 16384);
        uint4* dst = reinterpret_cast<uint4*>(As);
#pragma unroll
        for (int i = 0; i < 8; ++i) dst[i * 256 + tid] = src[i * 256 + tid];
    }
    __syncthreads();

    const int colTile = cg * 4 + wv;          // 0..15
    const half8* __restrict__ B = reinterpret_cast<const half8*>(Bp);

    f32x4 acc[4][4];
#pragma unroll
    for (int m = 0; m < 4; ++m)
#pragma unroll
        for (int n = 0; n < 4; ++n) acc[m][n] = (f32x4){0.f, 0.f, 0.f, 0.f};

#pragma unroll
    for (int kt = 0; kt < 8; ++kt) {
        half8 a[4], b[4];
#pragma unroll
        for (int m = 0; m < 4; ++m)
            a[m] = *reinterpret_cast<const half8*>(&As[((m * 8 + kt) * 64 + lane) * 8]);
#pragma unroll
        for (int n = 0; n < 4; ++n)
            b[n] = B[(size_t)(((colTile * 4 + n) * 8 + kt) * 64 + lane)];
#pragma unroll
        for (int m = 0; m < 4; ++m)
#pragma unroll
            for (int n = 0; n < 4; ++n)
                acc[m][n] = __builtin_amdgcn_mfma_f32_16x16x32_f16(a[m], b[n], acc[m][n], 0, 0, 0);
    }

    // epilogue: u32 key = (f2ord(score) & ~1023) | codeIdx ; top-2 per row
    const int cx = lane & 15;
    const int q  = lane >> 4;
    const int colBase = colTile * 64;
    float csv[4];
#pragma unroll
    for (int n = 0; n < 4; ++n) csv[n] = csq[colBase + n * 16 + cx];

#pragma unroll
    for (int m = 0; m < 4; ++m) {
#pragma unroll
        for (int r = 0; r < 4; ++r) {
            unsigned k0 = 0xFFFFFFFFu, k1 = 0xFFFFFFFFu;
#pragma unroll
            for (int n = 0; n < 4; ++n) {
                const float s = fmaf(-2.0f, acc[m][n][r], csv[n]);
                const unsigned key = (f2ord(s) & 0xFFFFFC00u)
                                   | (unsigned)(colBase + n * 16 + cx);
                if (key < k0) { k1 = k0; k0 = key; }
                else if (key < k1) { k1 = key; }
            }
#define MERGE_STEP(CTRL)                                              \
            {                                                         \
                const unsigned o0 = DPP_SELF(k0, CTRL);               \
                const unsigned o1 = DPP_SELF(k1, CTRL);               \
                const unsigned lo = (k0 < o0) ? k0 : o0;              \
                const unsigned hi = (k0 < o0) ? o0 : k0;              \
                const unsigned m1 = (k1 < o1) ? k1 : o1;              \
                k1 = (hi < m1) ? hi : m1;                             \
                k0 = lo;                                              \
            }
            MERGE_STEP(0x111)
            MERGE_STEP(0x112)
            MERGE_STEP(0x114)
            MERGE_STEP(0x118)
#undef MERGE_STEP
            if (cx == 15) red[wv][m * 16 + q * 4 + r] = make_uint2(k0, k1);
        }
    }
    __syncthreads();

    // cross-wave merge: 4 waves x 2 -> top-2 per row for this 256-col group
    if (tid < 64) {
        unsigned b0 = 0xFFFFFFFFu, b1 = 0xFFFFFFFFu;
#pragma unroll
        for (int w = 0; w < 4; ++w) {
            const uint2 v = red[w][tid];
            if (v.x < b0) { b1 = b0; b0 = v.x; } else if (v.x < b1) { b1 = v.x; }
            if (v.y < b0) { b1 = b0; b0 = v.y; } else if (v.y < b1) { b1 = v.y; }
        }
        const size_t row = (size_t)rowTile * 64 + tid;
        cand[row * 8 + cg * 2 + 0] = b0;
        cand[row * 8 + cg * 2 + 1] = b1;
    }
}

// ---------------- K3: exact fp32 rescore, ILP loads, register z_q ----------
__global__ __launch_bounds__(256) void vq_final(const float* __restrict__ z,
                                                const float* __restrict__ cb,
                                                const float* __restrict__ csq,
                                                const unsigned* __restrict__ cand,
                                                float* __restrict__ zq,
                                                float* __restrict__ outIdx) {
    const int lane = threadIdx.x & 63;
    const int row  = blockIdx.x * 4 + (threadIdx.x >> 6);

    const float4 zv = *reinterpret_cast<const float4*>(z + (size_t)row * DDIM + lane * 4);

    unsigned kk[8];
    *reinterpret_cast<uint4*>(&kk[0]) = *reinterpret_cast<const uint4*>(cand + (size_t)row * 8);
    *reinterpret_cast<uint4*>(&kk[4]) = *reinterpret_cast<const uint4*>(cand + (size_t)row * 8 + 4);

    // issue all 8 candidate row loads up front (coalesced 1 KB each)
    int idx0 = (int)(kk[0] & 1023u), idx1 = (int)(kk[1] & 1023u);
    int idx2 = (int)(kk[2] & 1023u), idx3 = (int)(kk[3] & 1023u);
    int idx4 = (int)(kk[4] & 1023u), idx5 = (int)(kk[5] & 1023u);
    int idx6 = (int)(kk[6] & 1023u), idx7 = (int)(kk[7] & 1023u);
    const float4 cv0 = *reinterpret_cast<const float4*>(cb + (size_t)idx0 * DDIM + lane * 4);
    const float4 cv1 = *reinterpret_cast<const float4*>(cb + (size_t)idx1 * DDIM + lane * 4);
    const float4 cv2 = *reinterpret_cast<const float4*>(cb + (size_t)idx2 * DDIM + lane * 4);
    const float4 cv3 = *reinterpret_cast<const float4*>(cb + (size_t)idx3 * DDIM + lane * 4);
    const float4 cv4 = *reinterpret_cast<const float4*>(cb + (size_t)idx4 * DDIM + lane * 4);
    const float4 cv5 = *reinterpret_cast<const float4*>(cb + (size_t)idx5 * DDIM + lane * 4);
    const float4 cv6 = *reinterpret_cast<const float4*>(cb + (size_t)idx6 * DDIM + lane * 4);
    const float4 cv7 = *reinterpret_cast<const float4*>(cb + (size_t)idx7 * DDIM + lane * 4);

#define DOT4(cv) fmaf(zv.x, (cv).x, fmaf(zv.y, (cv).y, fmaf(zv.z, (cv).z, zv.w * (cv).w)))
    float p0 = DOT4(cv0), p1 = DOT4(cv1), p2 = DOT4(cv2), p3 = DOT4(cv3);
    float p4 = DOT4(cv4), p5 = DOT4(cv5), p6 = DOT4(cv6), p7 = DOT4(cv7);
#undef DOT4

    // 8 independent DPP reduce chains (compiler interleaves -> ILP)
    p0 = dpp_radd(p0); p1 = dpp_radd(p1); p2 = dpp_radd(p2); p3 = dpp_radd(p3);
    p4 = dpp_radd(p4); p5 = dpp_radd(p5); p6 = dpp_radd(p6); p7 = dpp_radd(p7);

    // lane 63 holds all 8 totals; per-lane argmin chain, read back from 63
    float bestS = fmaf(-2.0f, p0, csq[idx0]);
    int   bestI = idx0, bestC = 0;
#define CHECK(c, pc, ic)                                                     \
    {                                                                        \
        const float s = fmaf(-2.0f, (pc), csq[ic]);                          \
        const bool t = (s < bestS) || (s == bestS && (ic) < bestI);          \
        bestS = t ? s : bestS; bestI = t ? (ic) : bestI; bestC = t ? (c) : bestC; \
    }
    CHECK(1, p1, idx1) CHECK(2, p2, idx2) CHECK(3, p3, idx3)
    CHECK(4, p4, idx4) CHECK(5, p5, idx5) CHECK(6, p6, idx6) CHECK(7, p7, idx7)
#undef CHECK

    const int bI = __builtin_amdgcn_readlane(bestI, 63);
    const int bC = __builtin_amdgcn_readlane(bestC, 63);

    if (lane == 0) outIdx[row] = (float)bI;

    // z_q from the already-loaded candidate registers (bC is wave-uniform)
    float4 q4 = cv0;
    if (bC == 1) q4 = cv1;
    if (bC == 2) q4 = cv2;
    if (bC == 3) q4 = cv3;
    if (bC == 4) q4 = cv4;
    if (bC == 5) q4 = cv5;
    if (bC == 6) q4 = cv6;
    if (bC == 7) q4 = cv7;
    *reinterpret_cast<float4*>(zq + (size_t)row * DDIM + lane * 4) = q4;
}

extern "C" void kernel_launch(void* const* d_in, const int* in_sizes, int n_in,
                              void* d_out, int out_size, void* d_ws, size_t ws_size,
                              hipStream_t stream) {
    const float* z  = (const float*)d_in[0];   // [16384,256]
    const float* cb = (const float*)d_in[1];   // [1024,256]
    float* out    = (float*)d_out;
    float* zq     = out;                            // 16.77 MB
    float* outIdx = out + (size_t)M_ROWS * DDIM;    // 64 KB

    // packed z (8 MB) lives in the z_q output region: scratch until vq_final
    _Float16* zhp = (_Float16*)d_out;

    char* ws = (char*)d_ws;
    _Float16* chp  = (_Float16*)ws;                       // 512 KB
    float* csq     = (float*)(ws + 512 * 1024);           // 4 KB
    unsigned* cand = (unsigned*)(ws + 512 * 1024 + 4096); // 512 KB

    vq_prep<<<2432, 256, 0, stream>>>(z, cb, zhp, chp, csq);
    dim3 sg(M_ROWS / 64, 4);
    vq_score<<<sg, 256, 0, stream>>>(zhp, chp, csq, cand);
    vq_final<<<M_ROWS / 4, 256, 0, stream>>>(z, cb, csq, cand, zq, outIdx);
}

// Round 12
// 39.937 us; speedup vs baseline: 1.7047x; 1.0559x over previous
//
#include <hip/hip_runtime.h>

// VectorQuantizer: fused (pack + fp16-MFMA filter + exact fp32 rescore).
// z_e [16,1024,256] f32, codebook [1024,256] f32
// out = concat( z_q [16,1024,256] f32 , indices [16,1024] as f32 )
//
// K1 vq_prep_cb: cb -> fp16 MFMA-fragment order + exact fp32 csq (proven).
// K2 vq_fused: 256 blocks x 1024 thr (16 waves, 1 block/CU, 104 KB LDS).
//   P1a: z rowTile (64 rows) -> LDS f32, XOR-swizzled (row&15 on float4 idx).
//   P1b: LDS f32 -> fp16 MFMA fragments in LDS (2-way-free bank pattern).
//   P2 : wave wv scores colTile wv (64 codes): 16x16x32 f16 MFMA acc[4][4],
//        u32 keys (truncated score | idx), DPP 16-lane top-2 -> red[16][64].
//   P3 : 4 rows/wave: merge 4-wave groups -> 8 cands (top-2 per 256 codes),
//        exact fp32 rescore (z from LDS, 8 ILP loads + 8 DPP chains),
//        argmin lane63, z_q selected from registers, store.
// NOTE: no __launch_bounds__ 2nd arg (clamps VGPR to 64 -> spills; R2/R7/R8).

#define M_ROWS 16384
#define DDIM   256
#define NCODES 1024

typedef _Float16 half8 __attribute__((ext_vector_type(8)));
typedef float    f32x4 __attribute__((ext_vector_type(4)));

__device__ __forceinline__ unsigned int f2ord(float f) {
    unsigned int u = __float_as_uint(f);
    return (u & 0x80000000u) ? ~u : (u | 0x80000000u);
}

#define DPP_SELF(k, ctrl) \
    ((unsigned)__builtin_amdgcn_update_dpp((int)(k), (int)(k), (ctrl), 0xF, 0xF, false))
#define DPP_Z(v, ctrl) \
    __builtin_amdgcn_update_dpp(0, (v), (ctrl), 0xF, 0xF, true)

// 64-lane sum via DPP; total valid in lane 63
__device__ __forceinline__ float dpp_radd(float x) {
    float s = x;
    s += __int_as_float(DPP_Z(__float_as_int(s), 0x111));
    s += __int_as_float(DPP_Z(__float_as_int(s), 0x112));
    s += __int_as_float(DPP_Z(__float_as_int(s), 0x114));
    s += __int_as_float(DPP_Z(__float_as_int(s), 0x118));
    s += __int_as_float(DPP_Z(__float_as_int(s), 0x142));
    s += __int_as_float(DPP_Z(__float_as_int(s), 0x143));
    return s;
}

// ---------------- K1: pack cb (blocks 0..127) + csq (blocks 128..383) ------
__global__ __launch_bounds__(256) void vq_prep_cb(const float* __restrict__ cb,
                                                  _Float16* __restrict__ chp,
                                                  float* __restrict__ csq) {
    if (blockIdx.x < 128) {
        const int gid = blockIdx.x * 256 + threadIdx.x;
        const int l   = gid & 63;
        const int g   = gid >> 6;
        const int kt  = g & 7;
        const int rt  = g >> 3;
        const int row = rt * 16 + (l & 15);
        const int k0  = kt * 32 + (l >> 4) * 8;
        const float4 v0 = *reinterpret_cast<const float4*>(cb + (size_t)row * DDIM + k0);
        const float4 v1 = *reinterpret_cast<const float4*>(cb + (size_t)row * DDIM + k0 + 4);
        half8 h;
        h[0] = (_Float16)v0.x; h[1] = (_Float16)v0.y; h[2] = (_Float16)v0.z; h[3] = (_Float16)v0.w;
        h[4] = (_Float16)v1.x; h[5] = (_Float16)v1.y; h[6] = (_Float16)v1.z; h[7] = (_Float16)v1.w;
        *reinterpret_cast<half8*>(chp + (size_t)gid * 8) = h;
    } else {
        const int code = (blockIdx.x - 128) * 4 + (threadIdx.x >> 6);
        const int lane = threadIdx.x & 63;
        const float4 v = *reinterpret_cast<const float4*>(cb + (size_t)code * DDIM + lane * 4);
        float s = v.x * v.x + v.y * v.y + v.z * v.z + v.w * v.w;
        s = dpp_radd(s);
        if (lane == 63) csq[code] = s;
    }
}

// ---------------- K2: fused pack + score + rescore + gather ----------------
__global__ __launch_bounds__(1024) void vq_fused(const float* __restrict__ z,
                                                 const _Float16* __restrict__ Bp,
                                                 const float* __restrict__ cb,
                                                 const float* __restrict__ csq,
                                                 float* __restrict__ zq,
                                                 float* __restrict__ outIdx) {
    __shared__ __align__(16) float    Zf[64 * 256];   // 64 KB, float4-swizzled
    __shared__ __align__(16) _Float16 Ah[64 * 256];   // 32 KB fragment-order
    __shared__ uint2 red[16][64];                     // 8 KB

    const int tid  = threadIdx.x;
    const int lane = tid & 63;
    const int wv   = tid >> 6;            // 0..15
    const int rowBase = blockIdx.x * 64;

    float4* Zf4 = reinterpret_cast<float4*>(Zf);

    // ---- P1a: z -> LDS f32, coalesced, swizzle float4-idx by (row&15) ----
    {
        const float4* zg = reinterpret_cast<const float4*>(z + (size_t)rowBase * DDIM);
#pragma unroll
        for (int j = 0; j < 4; ++j) {
            const int f   = j * 1024 + tid;   // 0..4095
            const int row = f >> 6;
            const int c4  = f & 63;
            Zf4[row * 64 + (c4 ^ (row & 15))] = zg[f];
        }
    }
    __syncthreads();

    // ---- P1b: LDS f32 -> fp16 fragments ----
#pragma unroll
    for (int i = 0; i < 2; ++i) {
        const int s   = i * 1024 + tid;   // 0..2047
        const int l   = s & 63;
        const int g   = s >> 6;           // 0..31 = m*8 + kt
        const int m   = g >> 3;
        const int kt  = g & 7;
        const int rowl = m * 16 + (l & 15);
        const int idx4 = kt * 8 + (l >> 4) * 2;
        const int swz  = rowl & 15;
        const float4 v0 = Zf4[rowl * 64 + ((idx4)     ^ swz)];
        const float4 v1 = Zf4[rowl * 64 + ((idx4 + 1) ^ swz)];
        half8 h;
        h[0] = (_Float16)v0.x; h[1] = (_Float16)v0.y; h[2] = (_Float16)v0.z; h[3] = (_Float16)v0.w;
        h[4] = (_Float16)v1.x; h[5] = (_Float16)v1.y; h[6] = (_Float16)v1.z; h[7] = (_Float16)v1.w;
        *reinterpret_cast<half8*>(&Ah[g * 512 + l * 8]) = h;
    }
    __syncthreads();

    // ---- P2: MFMA scores for colTile wv ----
    const half8* __restrict__ B = reinterpret_cast<const half8*>(Bp);
    const int colTile = wv;
    const int colBase = colTile * 64;
    const int cx = lane & 15;
    const int q  = lane >> 4;

    f32x4 acc[4][4];
#pragma unroll
    for (int m = 0; m < 4; ++m)
#pragma unroll
        for (int n = 0; n < 4; ++n) acc[m][n] = (f32x4){0.f, 0.f, 0.f, 0.f};

#pragma unroll
    for (int kt = 0; kt < 8; ++kt) {
        half8 a[4], b[4];
#pragma unroll
        for (int m = 0; m < 4; ++m)
            a[m] = *reinterpret_cast<const half8*>(&Ah[(m * 8 + kt) * 512 + lane * 8]);
#pragma unroll
        for (int n = 0; n < 4; ++n)
            b[n] = B[(size_t)(((colTile * 4 + n) * 8 + kt) * 64 + lane)];
#pragma unroll
        for (int m = 0; m < 4; ++m)
#pragma unroll
            for (int n = 0; n < 4; ++n)
                acc[m][n] = __builtin_amdgcn_mfma_f32_16x16x32_f16(a[m], b[n], acc[m][n], 0, 0, 0);
    }

    // epilogue: u32 keys, DPP 16-lane top-2 -> red[wv][row]
    float csv[4];
#pragma unroll
    for (int n = 0; n < 4; ++n) csv[n] = csq[colBase + n * 16 + cx];

#pragma unroll
    for (int m = 0; m < 4; ++m)
#pragma unroll
        for (int r = 0; r < 4; ++r) {
            unsigned k0 = 0xFFFFFFFFu, k1 = 0xFFFFFFFFu;
#pragma unroll
            for (int n = 0; n < 4; ++n) {
                const float s = fmaf(-2.0f, acc[m][n][r], csv[n]);
                const unsigned key = (f2ord(s) & 0xFFFFFC00u)
                                   | (unsigned)(colBase + n * 16 + cx);
                if (key < k0) { k1 = k0; k0 = key; }
                else if (key < k1) { k1 = key; }
            }
#define MERGE_STEP(CTRL)                                              \
            {                                                         \
                const unsigned o0 = DPP_SELF(k0, CTRL);               \
                const unsigned o1 = DPP_SELF(k1, CTRL);               \
                const unsigned lo = (k0 < o0) ? k0 : o0;              \
                const unsigned hi = (k0 < o0) ? o0 : k0;              \
                const unsigned m1 = (k1 < o1) ? k1 : o1;              \
                k1 = (hi < m1) ? hi : m1;                             \
                k0 = lo;                                              \
            }
            MERGE_STEP(0x111)
            MERGE_STEP(0x112)
            MERGE_STEP(0x114)
            MERGE_STEP(0x118)
#undef MERGE_STEP
            if (cx == 15) red[wv][m * 16 + q * 4 + r] = make_uint2(k0, k1);
        }
    __syncthreads();

    // ---- P3: 4 rows per wave; merge -> 8 cands; exact rescore; gather ----
#pragma unroll
    for (int i = 0; i < 4; ++i) {
        const int rl  = wv * 4 + i;
        const int row = rowBase + rl;

        unsigned kk[8];
#pragma unroll
        for (int g4 = 0; g4 < 4; ++g4) {
            unsigned b0 = 0xFFFFFFFFu, b1 = 0xFFFFFFFFu;
#pragma unroll
            for (int w = 0; w < 4; ++w) {
                const uint2 v = red[g4 * 4 + w][rl];
                if (v.x < b0) { b1 = b0; b0 = v.x; } else if (v.x < b1) { b1 = v.x; }
                if (v.y < b0) { b1 = b0; b0 = v.y; } else if (v.y < b1) { b1 = v.y; }
            }
            kk[2 * g4] = b0; kk[2 * g4 + 1] = b1;
        }

        const float4 zv = Zf4[rl * 64 + (lane ^ (rl & 15))];

        const int idx0 = (int)(kk[0] & 1023u), idx1 = (int)(kk[1] & 1023u);
        const int idx2 = (int)(kk[2] & 1023u), idx3 = (int)(kk[3] & 1023u);
        const int idx4 = (int)(kk[4] & 1023u), idx5 = (int)(kk[5] & 1023u);
        const int idx6 = (int)(kk[6] & 1023u), idx7 = (int)(kk[7] & 1023u);
        const float4 cv0 = *reinterpret_cast<const float4*>(cb + (size_t)idx0 * DDIM + lane * 4);
        const float4 cv1 = *reinterpret_cast<const float4*>(cb + (size_t)idx1 * DDIM + lane * 4);
        const float4 cv2 = *reinterpret_cast<const float4*>(cb + (size_t)idx2 * DDIM + lane * 4);
        const float4 cv3 = *reinterpret_cast<const float4*>(cb + (size_t)idx3 * DDIM + lane * 4);
        const float4 cv4 = *reinterpret_cast<const float4*>(cb + (size_t)idx4 * DDIM + lane * 4);
        const float4 cv5 = *reinterpret_cast<const float4*>(cb + (size_t)idx5 * DDIM + lane * 4);
        const float4 cv6 = *reinterpret_cast<const float4*>(cb + (size_t)idx6 * DDIM + lane * 4);
        const float4 cv7 = *reinterpret_cast<const float4*>(cb + (size_t)idx7 * DDIM + lane * 4);

#define DOT4(cv) fmaf(zv.x, (cv).x, fmaf(zv.y, (cv).y, fmaf(zv.z, (cv).z, zv.w * (cv).w)))
        float p0 = DOT4(cv0), p1 = DOT4(cv1), p2 = DOT4(cv2), p3 = DOT4(cv3);
        float p4 = DOT4(cv4), p5 = DOT4(cv5), p6 = DOT4(cv6), p7 = DOT4(cv7);
#undef DOT4

        p0 = dpp_radd(p0); p1 = dpp_radd(p1); p2 = dpp_radd(p2); p3 = dpp_radd(p3);
        p4 = dpp_radd(p4); p5 = dpp_radd(p5); p6 = dpp_radd(p6); p7 = dpp_radd(p7);

        float bestS = fmaf(-2.0f, p0, csq[idx0]);
        int   bestI = idx0, bestC = 0;
#define CHECK(c, pc, ic)                                                     \
        {                                                                    \
            const float s = fmaf(-2.0f, (pc), csq[ic]);                      \
            const bool t = (s < bestS) || (s == bestS && (ic) < bestI);      \
            bestS = t ? s : bestS; bestI = t ? (ic) : bestI; bestC = t ? (c) : bestC; \
        }
        CHECK(1, p1, idx1) CHECK(2, p2, idx2) CHECK(3, p3, idx3)
        CHECK(4, p4, idx4) CHECK(5, p5, idx5) CHECK(6, p6, idx6) CHECK(7, p7, idx7)
#undef CHECK

        const int bI = __builtin_amdgcn_readlane(bestI, 63);
        const int bC = __builtin_amdgcn_readlane(bestC, 63);

        if (lane == 0) outIdx[row] = (float)bI;

        float4 q4 = cv0;
        if (bC == 1) q4 = cv1;
        if (bC == 2) q4 = cv2;
        if (bC == 3) q4 = cv3;
        if (bC == 4) q4 = cv4;
        if (bC == 5) q4 = cv5;
        if (bC == 6) q4 = cv6;
        if (bC == 7) q4 = cv7;
        *reinterpret_cast<float4*>(zq + (size_t)row * DDIM + lane * 4) = q4;
    }
}

extern "C" void kernel_launch(void* const* d_in, const int* in_sizes, int n_in,
                              void* d_out, int out_size, void* d_ws, size_t ws_size,
                              hipStream_t stream) {
    const float* z  = (const float*)d_in[0];   // [16384,256]
    const float* cb = (const float*)d_in[1];   // [1024,256]
    float* out    = (float*)d_out;
    float* zq     = out;                            // 16.77 MB
    float* outIdx = out + (size_t)M_ROWS * DDIM;    // 64 KB

    char* ws = (char*)d_ws;
    _Float16* chp = (_Float16*)ws;                  // 512 KB
    float* csq    = (float*)(ws + 512 * 1024);      // 4 KB

    vq_prep_cb<<<384, 256, 0, stream>>>(cb, chp, csq);
    vq_fused<<<M_ROWS / 64, 1024, 0, stream>>>(z, chp, cb, csq, zq, outIdx);
}

// Round 13
// 39.517 us; speedup vs baseline: 1.7228x; 1.0106x over previous
//
#include <hip/hip_runtime.h>

// VectorQuantizer: fused (pack + fp16-MFMA filter + exact fp32 rescore).
// z_e [16,1024,256] f32, codebook [1024,256] f32
// out = concat( z_q [16,1024,256] f32 , indices [16,1024] as f32 )
//
// K1 vq_prep_cb: cb -> fp16 MFMA-fragment order + exact fp32 csq (proven).
// K2 vq_fused: 512 blocks x 512 thr (8 waves), 32 rows/block, 20 KB LDS
//   -> 2 blocks/CU co-resident (desynchronized phases overlap stalls).
//   P1: z -> fp16 MFMA fragments in LDS, direct from global (R8 pattern).
//   P2: wave wv scores colTiles wv*2, wv*2+1 (2 x 64 codes): 16x16x32 f16
//       MFMA acc[2][4]; u32 keys, DPP 16-lane top-2 -> red[16][32].
//   P3: 4 rows/wave: merge 4 colTiles -> 8 cands (top-2 per 256 codes),
//       exact fp32 rescore (z re-read from global, L2-hot; 8 ILP loads +
//       8 DPP chains), argmin lane63, z_q from registers, store.
// NOTE: no __launch_bounds__ 2nd arg (clamps VGPR to 64 -> spills; R2/R7/R8).

#define M_ROWS 16384
#define DDIM   256
#define NCODES 1024

typedef _Float16 half8 __attribute__((ext_vector_type(8)));
typedef float    f32x4 __attribute__((ext_vector_type(4)));

__device__ __forceinline__ unsigned int f2ord(float f) {
    unsigned int u = __float_as_uint(f);
    return (u & 0x80000000u) ? ~u : (u | 0x80000000u);
}

#define DPP_SELF(k, ctrl) \
    ((unsigned)__builtin_amdgcn_update_dpp((int)(k), (int)(k), (ctrl), 0xF, 0xF, false))
#define DPP_Z(v, ctrl) \
    __builtin_amdgcn_update_dpp(0, (v), (ctrl), 0xF, 0xF, true)

// 64-lane sum via DPP; total valid in lane 63
__device__ __forceinline__ float dpp_radd(float x) {
    float s = x;
    s += __int_as_float(DPP_Z(__float_as_int(s), 0x111));
    s += __int_as_float(DPP_Z(__float_as_int(s), 0x112));
    s += __int_as_float(DPP_Z(__float_as_int(s), 0x114));
    s += __int_as_float(DPP_Z(__float_as_int(s), 0x118));
    s += __int_as_float(DPP_Z(__float_as_int(s), 0x142));
    s += __int_as_float(DPP_Z(__float_as_int(s), 0x143));
    return s;
}

// ---------------- K1: pack cb (blocks 0..127) + csq (blocks 128..383) ------
__global__ __launch_bounds__(256) void vq_prep_cb(const float* __restrict__ cb,
                                                  _Float16* __restrict__ chp,
                                                  float* __restrict__ csq) {
    if (blockIdx.x < 128) {
        const int gid = blockIdx.x * 256 + threadIdx.x;
        const int l   = gid & 63;
        const int g   = gid >> 6;
        const int kt  = g & 7;
        const int rt  = g >> 3;
        const int row = rt * 16 + (l & 15);
        const int k0  = kt * 32 + (l >> 4) * 8;
        const float4 v0 = *reinterpret_cast<const float4*>(cb + (size_t)row * DDIM + k0);
        const float4 v1 = *reinterpret_cast<const float4*>(cb + (size_t)row * DDIM + k0 + 4);
        half8 h;
        h[0] = (_Float16)v0.x; h[1] = (_Float16)v0.y; h[2] = (_Float16)v0.z; h[3] = (_Float16)v0.w;
        h[4] = (_Float16)v1.x; h[5] = (_Float16)v1.y; h[6] = (_Float16)v1.z; h[7] = (_Float16)v1.w;
        *reinterpret_cast<half8*>(chp + (size_t)gid * 8) = h;
    } else {
        const int code = (blockIdx.x - 128) * 4 + (threadIdx.x >> 6);
        const int lane = threadIdx.x & 63;
        const float4 v = *reinterpret_cast<const float4*>(cb + (size_t)code * DDIM + lane * 4);
        float s = v.x * v.x + v.y * v.y + v.z * v.z + v.w * v.w;
        s = dpp_radd(s);
        if (lane == 63) csq[code] = s;
    }
}

// ---------------- K2: fused pack + score + rescore + gather ----------------
__global__ __launch_bounds__(512) void vq_fused(const float* __restrict__ z,
                                                const _Float16* __restrict__ Bp,
                                                const float* __restrict__ cb,
                                                const float* __restrict__ csq,
                                                float* __restrict__ zq,
                                                float* __restrict__ outIdx) {
    __shared__ __align__(16) _Float16 Ah[32 * 256];   // 16 KB fragment-order
    __shared__ uint2 red[16][32];                     // 4 KB top-2 per tile/row

    const int tid  = threadIdx.x;
    const int lane = tid & 63;
    const int wv   = tid >> 6;            // 0..7
    const int rowBase = blockIdx.x * 32;

    // ---- P1: stage 32 rows as fp16 fragments, direct from global ----
#pragma unroll
    for (int i = 0; i < 2; ++i) {
        const int slot = i * 512 + tid;   // 0..1023
        const int l  = slot & 63;
        const int g  = slot >> 6;         // 0..15 = m*8 + kt
        const int m  = g >> 3;
        const int kt = g & 7;
        const int row = rowBase + m * 16 + (l & 15);
        const int k0  = kt * 32 + (l >> 4) * 8;
        const float4 v0 = *reinterpret_cast<const float4*>(z + (size_t)row * DDIM + k0);
        const float4 v1 = *reinterpret_cast<const float4*>(z + (size_t)row * DDIM + k0 + 4);
        half8 h;
        h[0] = (_Float16)v0.x; h[1] = (_Float16)v0.y; h[2] = (_Float16)v0.z; h[3] = (_Float16)v0.w;
        h[4] = (_Float16)v1.x; h[5] = (_Float16)v1.y; h[6] = (_Float16)v1.z; h[7] = (_Float16)v1.w;
        *reinterpret_cast<half8*>(&Ah[g * 512 + l * 8]) = h;
    }
    __syncthreads();

    // ---- P2: MFMA scores for colTiles wv*2, wv*2+1 ----
    const half8* __restrict__ B = reinterpret_cast<const half8*>(Bp);
    const int cx = lane & 15;
    const int q  = lane >> 4;

#pragma unroll
    for (int ct = 0; ct < 2; ++ct) {
        const int colTile = wv * 2 + ct;      // 0..15
        const int colBase = colTile * 64;

        f32x4 acc[2][4];
#pragma unroll
        for (int m = 0; m < 2; ++m)
#pragma unroll
            for (int n = 0; n < 4; ++n) acc[m][n] = (f32x4){0.f, 0.f, 0.f, 0.f};

#pragma unroll
        for (int kt = 0; kt < 8; ++kt) {
            half8 a[2], b[4];
#pragma unroll
            for (int m = 0; m < 2; ++m)
                a[m] = *reinterpret_cast<const half8*>(&Ah[(m * 8 + kt) * 512 + lane * 8]);
#pragma unroll
            for (int n = 0; n < 4; ++n)
                b[n] = B[(size_t)(((colTile * 4 + n) * 8 + kt) * 64 + lane)];
#pragma unroll
            for (int m = 0; m < 2; ++m)
#pragma unroll
                for (int n = 0; n < 4; ++n)
                    acc[m][n] = __builtin_amdgcn_mfma_f32_16x16x32_f16(a[m], b[n], acc[m][n], 0, 0, 0);
        }

        float csv[4];
#pragma unroll
        for (int n = 0; n < 4; ++n) csv[n] = csq[colBase + n * 16 + cx];

#pragma unroll
        for (int m = 0; m < 2; ++m)
#pragma unroll
            for (int r = 0; r < 4; ++r) {
                unsigned k0 = 0xFFFFFFFFu, k1 = 0xFFFFFFFFu;
#pragma unroll
                for (int n = 0; n < 4; ++n) {
                    const float s = fmaf(-2.0f, acc[m][n][r], csv[n]);
                    const unsigned key = (f2ord(s) & 0xFFFFFC00u)
                                       | (unsigned)(colBase + n * 16 + cx);
                    if (key < k0) { k1 = k0; k0 = key; }
                    else if (key < k1) { k1 = key; }
                }
#define MERGE_STEP(CTRL)                                              \
                {                                                     \
                    const unsigned o0 = DPP_SELF(k0, CTRL);           \
                    const unsigned o1 = DPP_SELF(k1, CTRL);           \
                    const unsigned lo = (k0 < o0) ? k0 : o0;          \
                    const unsigned hi = (k0 < o0) ? o0 : k0;          \
                    const unsigned m1 = (k1 < o1) ? k1 : o1;          \
                    k1 = (hi < m1) ? hi : m1;                         \
                    k0 = lo;                                          \
                }
                MERGE_STEP(0x111)
                MERGE_STEP(0x112)
                MERGE_STEP(0x114)
                MERGE_STEP(0x118)
#undef MERGE_STEP
                if (cx == 15) red[colTile][m * 16 + q * 4 + r] = make_uint2(k0, k1);
            }
    }
    __syncthreads();

    // ---- P3: 4 rows per wave; merge -> 8 cands; exact rescore; gather ----
#pragma unroll
    for (int i = 0; i < 4; ++i) {
        const int rl  = wv * 4 + i;
        const int row = rowBase + rl;

        unsigned kk[8];
#pragma unroll
        for (int g4 = 0; g4 < 4; ++g4) {
            unsigned b0 = 0xFFFFFFFFu, b1 = 0xFFFFFFFFu;
#pragma unroll
            for (int w = 0; w < 4; ++w) {
                const uint2 v = red[g4 * 4 + w][rl];
                if (v.x < b0) { b1 = b0; b0 = v.x; } else if (v.x < b1) { b1 = v.x; }
                if (v.y < b0) { b1 = b0; b0 = v.y; } else if (v.y < b1) { b1 = v.y; }
            }
            kk[2 * g4] = b0; kk[2 * g4 + 1] = b1;
        }

        const float4 zv = *reinterpret_cast<const float4*>(z + (size_t)row * DDIM + lane * 4);

        const int idx0 = (int)(kk[0] & 1023u), idx1 = (int)(kk[1] & 1023u);
        const int idx2 = (int)(kk[2] & 1023u), idx3 = (int)(kk[3] & 1023u);
        const int idx4 = (int)(kk[4] & 1023u), idx5 = (int)(kk[5] & 1023u);
        const int idx6 = (int)(kk[6] & 1023u), idx7 = (int)(kk[7] & 1023u);
        const float4 cv0 = *reinterpret_cast<const float4*>(cb + (size_t)idx0 * DDIM + lane * 4);
        const float4 cv1 = *reinterpret_cast<const float4*>(cb + (size_t)idx1 * DDIM + lane * 4);
        const float4 cv2 = *reinterpret_cast<const float4*>(cb + (size_t)idx2 * DDIM + lane * 4);
        const float4 cv3 = *reinterpret_cast<const float4*>(cb + (size_t)idx3 * DDIM + lane * 4);
        const float4 cv4 = *reinterpret_cast<const float4*>(cb + (size_t)idx4 * DDIM + lane * 4);
        const float4 cv5 = *reinterpret_cast<const float4*>(cb + (size_t)idx5 * DDIM + lane * 4);
        const float4 cv6 = *reinterpret_cast<const float4*>(cb + (size_t)idx6 * DDIM + lane * 4);
        const float4 cv7 = *reinterpret_cast<const float4*>(cb + (size_t)idx7 * DDIM + lane * 4);

#define DOT4(cv) fmaf(zv.x, (cv).x, fmaf(zv.y, (cv).y, fmaf(zv.z, (cv).z, zv.w * (cv).w)))
        float p0 = DOT4(cv0), p1 = DOT4(cv1), p2 = DOT4(cv2), p3 = DOT4(cv3);
        float p4 = DOT4(cv4), p5 = DOT4(cv5), p6 = DOT4(cv6), p7 = DOT4(cv7);
#undef DOT4

        p0 = dpp_radd(p0); p1 = dpp_radd(p1); p2 = dpp_radd(p2); p3 = dpp_radd(p3);
        p4 = dpp_radd(p4); p5 = dpp_radd(p5); p6 = dpp_radd(p6); p7 = dpp_radd(p7);

        float bestS = fmaf(-2.0f, p0, csq[idx0]);
        int   bestI = idx0, bestC = 0;
#define CHECK(c, pc, ic)                                                     \
        {                                                                    \
            const float s = fmaf(-2.0f, (pc), csq[ic]);                      \
            const bool t = (s < bestS) || (s == bestS && (ic) < bestI);      \
            bestS = t ? s : bestS; bestI = t ? (ic) : bestI; bestC = t ? (c) : bestC; \
        }
        CHECK(1, p1, idx1) CHECK(2, p2, idx2) CHECK(3, p3, idx3)
        CHECK(4, p4, idx4) CHECK(5, p5, idx5) CHECK(6, p6, idx6) CHECK(7, p7, idx7)
#undef CHECK

        const int bI = __builtin_amdgcn_readlane(bestI, 63);
        const int bC = __builtin_amdgcn_readlane(bestC, 63);

        if (lane == 0) outIdx[row] = (float)bI;

        float4 q4 = cv0;
        if (bC == 1) q4 = cv1;
        if (bC == 2) q4 = cv2;
        if (bC == 3) q4 = cv3;
        if (bC == 4) q4 = cv4;
        if (bC == 5) q4 = cv5;
        if (bC == 6) q4 = cv6;
        if (bC == 7) q4 = cv7;
        *reinterpret_cast<float4*>(zq + (size_t)row * DDIM + lane * 4) = q4;
    }
}

extern "C" void kernel_launch(void* const* d_in, const int* in_sizes, int n_in,
                              void* d_out, int out_size, void* d_ws, size_t ws_size,
                              hipStream_t stream) {
    const float* z  = (const float*)d_in[0];   // [16384,256]
    const float* cb = (const float*)d_in[1];   // [1024,256]
    float* out    = (float*)d_out;
    float* zq     = out;                            // 16.77 MB
    float* outIdx = out + (size_t)M_ROWS * DDIM;    // 64 KB

    char* ws = (char*)d_ws;
    _Float16* chp = (_Float16*)ws;                  // 512 KB
    float* csq    = (float*)(ws + 512 * 1024);      // 4 KB

    vq_prep_cb<<<384, 256, 0, stream>>>(cb, chp, csq);
    vq_fused<<<M_ROWS / 32, 512, 0, stream>>>(z, chp, cb, csq, zq, outIdx);
}

// Round 14
// 38.736 us; speedup vs baseline: 1.7576x; 1.0202x over previous
//
#include <hip/hip_runtime.h>

// VectorQuantizer: fused (pack + fp16-MFMA filter + exact fp32 rescore).
// z_e [16,1024,256] f32, codebook [1024,256] f32
// out = concat( z_q [16,1024,256] f32 , indices [16,1024] as f32 )
//
// K1 vq_prep_cb: cb -> fp16 MFMA-fragment order + exact fp32 csq (proven).
// K2 vq_fused: 256 blocks x 512 thr (8 waves), 64 rows/block, 40 KB LDS.
//   P1: z -> fp16 MFMA fragments in LDS (direct from global).
//   P2: wave wv scores colTiles wv*2, wv*2+1 (2 x 64 codes): 16x16x32 f16
//       MFMA acc[4][4]; u32 keys (truncated score | idx), DPP 16-lane top-2
//       -> red[16][64].
//   P3: 8 rows/wave: merge 4-tile groups -> 8 cands (top-2 per 256 codes);
//       EARLY-EXIT: if approx top-2 margin > 0.15 (>>max fp16+trunc error),
//       approx winner is provably exact -> gather only winner row.
//       Else full exact fp32 rescore (8 ILP loads + 8 DPP chains).
// NOTE: no __launch_bounds__ 2nd arg (clamps VGPR to 64 -> spills; R2/R7/R8).

#define M_ROWS 16384
#define DDIM   256
#define NCODES 1024

typedef _Float16 half8 __attribute__((ext_vector_type(8)));
typedef float    f32x4 __attribute__((ext_vector_type(4)));

__device__ __forceinline__ unsigned int f2ord(float f) {
    unsigned int u = __float_as_uint(f);
    return (u & 0x80000000u) ? ~u : (u | 0x80000000u);
}
// inverse of f2ord (pass key with low 10 bits masked off)
__device__ __forceinline__ float ord2f(unsigned o) {
    unsigned u = (o & 0x80000000u) ? (o & 0x7FFFFFFFu) : ~o;
    return __uint_as_float(u);
}

#define DPP_SELF(k, ctrl) \
    ((unsigned)__builtin_amdgcn_update_dpp((int)(k), (int)(k), (ctrl), 0xF, 0xF, false))
#define DPP_Z(v, ctrl) \
    __builtin_amdgcn_update_dpp(0, (v), (ctrl), 0xF, 0xF, true)

// 64-lane sum via DPP; total valid in lane 63
__device__ __forceinline__ float dpp_radd(float x) {
    float s = x;
    s += __int_as_float(DPP_Z(__float_as_int(s), 0x111));
    s += __int_as_float(DPP_Z(__float_as_int(s), 0x112));
    s += __int_as_float(DPP_Z(__float_as_int(s), 0x114));
    s += __int_as_float(DPP_Z(__float_as_int(s), 0x118));
    s += __int_as_float(DPP_Z(__float_as_int(s), 0x142));
    s += __int_as_float(DPP_Z(__float_as_int(s), 0x143));
    return s;
}

// ---------------- K1: pack cb (blocks 0..127) + csq (blocks 128..383) ------
__global__ __launch_bounds__(256) void vq_prep_cb(const float* __restrict__ cb,
                                                  _Float16* __restrict__ chp,
                                                  float* __restrict__ csq) {
    if (blockIdx.x < 128) {
        const int gid = blockIdx.x * 256 + threadIdx.x;
        const int l   = gid & 63;
        const int g   = gid >> 6;
        const int kt  = g & 7;
        const int rt  = g >> 3;
        const int row = rt * 16 + (l & 15);
        const int k0  = kt * 32 + (l >> 4) * 8;
        const float4 v0 = *reinterpret_cast<const float4*>(cb + (size_t)row * DDIM + k0);
        const float4 v1 = *reinterpret_cast<const float4*>(cb + (size_t)row * DDIM + k0 + 4);
        half8 h;
        h[0] = (_Float16)v0.x; h[1] = (_Float16)v0.y; h[2] = (_Float16)v0.z; h[3] = (_Float16)v0.w;
        h[4] = (_Float16)v1.x; h[5] = (_Float16)v1.y; h[6] = (_Float16)v1.z; h[7] = (_Float16)v1.w;
        *reinterpret_cast<half8*>(chp + (size_t)gid * 8) = h;
    } else {
        const int code = (blockIdx.x - 128) * 4 + (threadIdx.x >> 6);
        const int lane = threadIdx.x & 63;
        const float4 v = *reinterpret_cast<const float4*>(cb + (size_t)code * DDIM + lane * 4);
        float s = v.x * v.x + v.y * v.y + v.z * v.z + v.w * v.w;
        s = dpp_radd(s);
        if (lane == 63) csq[code] = s;
    }
}

// ---------------- K2: fused pack + score + select + rescore + gather -------
__global__ __launch_bounds__(512) void vq_fused(const float* __restrict__ z,
                                                const _Float16* __restrict__ Bp,
                                                const float* __restrict__ cb,
                                                const float* __restrict__ csq,
                                                float* __restrict__ zq,
                                                float* __restrict__ outIdx) {
    __shared__ __align__(16) _Float16 Ah[64 * 256];   // 32 KB fragment-order
    __shared__ uint2 red[16][64];                     // 8 KB top-2 per tile/row

    const int tid  = threadIdx.x;
    const int lane = tid & 63;
    const int wv   = tid >> 6;            // 0..7
    const int rowBase = blockIdx.x * 64;

    // ---- P1: stage 64 rows as fp16 fragments, direct from global ----
#pragma unroll
    for (int i = 0; i < 4; ++i) {
        const int slot = i * 512 + tid;   // 0..2047
        const int l  = slot & 63;
        const int g  = slot >> 6;         // 0..31 = m*8 + kt
        const int m  = g >> 3;
        const int kt = g & 7;
        const int row = rowBase + m * 16 + (l & 15);
        const int k0  = kt * 32 + (l >> 4) * 8;
        const float4 v0 = *reinterpret_cast<const float4*>(z + (size_t)row * DDIM + k0);
        const float4 v1 = *reinterpret_cast<const float4*>(z + (size_t)row * DDIM + k0 + 4);
        half8 h;
        h[0] = (_Float16)v0.x; h[1] = (_Float16)v0.y; h[2] = (_Float16)v0.z; h[3] = (_Float16)v0.w;
        h[4] = (_Float16)v1.x; h[5] = (_Float16)v1.y; h[6] = (_Float16)v1.z; h[7] = (_Float16)v1.w;
        *reinterpret_cast<half8*>(&Ah[g * 512 + l * 8]) = h;
    }
    __syncthreads();

    // ---- P2: MFMA scores for colTiles wv*2, wv*2+1 ----
    const half8* __restrict__ B = reinterpret_cast<const half8*>(Bp);
    const int cx = lane & 15;
    const int q  = lane >> 4;

    for (int ct = 0; ct < 2; ++ct) {
        const int colTile = wv * 2 + ct;      // 0..15
        const int colBase = colTile * 64;

        f32x4 acc[4][4];
#pragma unroll
        for (int m = 0; m < 4; ++m)
#pragma unroll
            for (int n = 0; n < 4; ++n) acc[m][n] = (f32x4){0.f, 0.f, 0.f, 0.f};

#pragma unroll
        for (int kt = 0; kt < 8; ++kt) {
            half8 a[4], b[4];
#pragma unroll
            for (int m = 0; m < 4; ++m)
                a[m] = *reinterpret_cast<const half8*>(&Ah[(m * 8 + kt) * 512 + lane * 8]);
#pragma unroll
            for (int n = 0; n < 4; ++n)
                b[n] = B[(size_t)(((colTile * 4 + n) * 8 + kt) * 64 + lane)];
#pragma unroll
            for (int m = 0; m < 4; ++m)
#pragma unroll
                for (int n = 0; n < 4; ++n)
                    acc[m][n] = __builtin_amdgcn_mfma_f32_16x16x32_f16(a[m], b[n], acc[m][n], 0, 0, 0);
        }

        float csv[4];
#pragma unroll
        for (int n = 0; n < 4; ++n) csv[n] = csq[colBase + n * 16 + cx];

#pragma unroll
        for (int m = 0; m < 4; ++m)
#pragma unroll
            for (int r = 0; r < 4; ++r) {
                unsigned k0 = 0xFFFFFFFFu, k1 = 0xFFFFFFFFu;
#pragma unroll
                for (int n = 0; n < 4; ++n) {
                    const float s = fmaf(-2.0f, acc[m][n][r], csv[n]);
                    const unsigned key = (f2ord(s) & 0xFFFFFC00u)
                                       | (unsigned)(colBase + n * 16 + cx);
                    if (key < k0) { k1 = k0; k0 = key; }
                    else if (key < k1) { k1 = key; }
                }
#define MERGE_STEP(CTRL)                                              \
                {                                                     \
                    const unsigned o0 = DPP_SELF(k0, CTRL);           \
                    const unsigned o1 = DPP_SELF(k1, CTRL);           \
                    const unsigned lo = (k0 < o0) ? k0 : o0;          \
                    const unsigned hi = (k0 < o0) ? o0 : k0;          \
                    const unsigned m1 = (k1 < o1) ? k1 : o1;          \
                    k1 = (hi < m1) ? hi : m1;                         \
                    k0 = lo;                                          \
                }
                MERGE_STEP(0x111)
                MERGE_STEP(0x112)
                MERGE_STEP(0x114)
                MERGE_STEP(0x118)
#undef MERGE_STEP
                if (cx == 15) red[colTile][m * 16 + q * 4 + r] = make_uint2(k0, k1);
            }
    }
    __syncthreads();

    // ---- P3: 8 rows per wave; merge -> 8 cands; margin test; rescore ----
#pragma unroll 1
    for (int i = 0; i < 8; ++i) {
        const int rl  = wv * 8 + i;
        const int row = rowBase + rl;

        unsigned kk[8];
#pragma unroll
        for (int g4 = 0; g4 < 4; ++g4) {
            unsigned b0 = 0xFFFFFFFFu, b1 = 0xFFFFFFFFu;
#pragma unroll
            for (int w = 0; w < 4; ++w) {
                const uint2 v = red[g4 * 4 + w][rl];
                if (v.x < b0) { b1 = b0; b0 = v.x; } else if (v.x < b1) { b1 = v.x; }
                if (v.y < b0) { b1 = b0; b0 = v.y; } else if (v.y < b1) { b1 = v.y; }
            }
            kk[2 * g4] = b0; kk[2 * g4 + 1] = b1;
        }

        // global approx top-2 and margin (identical across lanes -> uniform)
        unsigned m0 = 0xFFFFFFFFu, m1 = 0xFFFFFFFFu;
#pragma unroll
        for (int c = 0; c < 8; ++c) {
            const unsigned k = kk[c];
            if (k < m0) { m1 = m0; m0 = k; } else if (k < m1) { m1 = k; }
        }
        const float s0 = ord2f(m0 & 0xFFFFFC00u);
        const float s1 = ord2f(m1 & 0xFFFFFC00u);

        if (s1 - s0 > 0.15f) {
            // margin >> max approx error: approx winner is provably exact
            const int bI = (int)(m0 & 1023u);
            if (lane == 0) outIdx[row] = (float)bI;
            const float4 q4 = *reinterpret_cast<const float4*>(cb + (size_t)bI * DDIM + lane * 4);
            *reinterpret_cast<float4*>(zq + (size_t)row * DDIM + lane * 4) = q4;
            continue;
        }

        const float4 zv = *reinterpret_cast<const float4*>(z + (size_t)row * DDIM + lane * 4);

        const int idx0 = (int)(kk[0] & 1023u), idx1 = (int)(kk[1] & 1023u);
        const int idx2 = (int)(kk[2] & 1023u), idx3 = (int)(kk[3] & 1023u);
        const int idx4 = (int)(kk[4] & 1023u), idx5 = (int)(kk[5] & 1023u);
        const int idx6 = (int)(kk[6] & 1023u), idx7 = (int)(kk[7] & 1023u);
        const float4 cv0 = *reinterpret_cast<const float4*>(cb + (size_t)idx0 * DDIM + lane * 4);
        const float4 cv1 = *reinterpret_cast<const float4*>(cb + (size_t)idx1 * DDIM + lane * 4);
        const float4 cv2 = *reinterpret_cast<const float4*>(cb + (size_t)idx2 * DDIM + lane * 4);
        const float4 cv3 = *reinterpret_cast<const float4*>(cb + (size_t)idx3 * DDIM + lane * 4);
        const float4 cv4 = *reinterpret_cast<const float4*>(cb + (size_t)idx4 * DDIM + lane * 4);
        const float4 cv5 = *reinterpret_cast<const float4*>(cb + (size_t)idx5 * DDIM + lane * 4);
        const float4 cv6 = *reinterpret_cast<const float4*>(cb + (size_t)idx6 * DDIM + lane * 4);
        const float4 cv7 = *reinterpret_cast<const float4*>(cb + (size_t)idx7 * DDIM + lane * 4);

#define DOT4(cv) fmaf(zv.x, (cv).x, fmaf(zv.y, (cv).y, fmaf(zv.z, (cv).z, zv.w * (cv).w)))
        float p0 = DOT4(cv0), p1 = DOT4(cv1), p2 = DOT4(cv2), p3 = DOT4(cv3);
        float p4 = DOT4(cv4), p5 = DOT4(cv5), p6 = DOT4(cv6), p7 = DOT4(cv7);
#undef DOT4

        p0 = dpp_radd(p0); p1 = dpp_radd(p1); p2 = dpp_radd(p2); p3 = dpp_radd(p3);
        p4 = dpp_radd(p4); p5 = dpp_radd(p5); p6 = dpp_radd(p6); p7 = dpp_radd(p7);

        float bestS = fmaf(-2.0f, p0, csq[idx0]);
        int   bestI = idx0, bestC = 0;
#define CHECK(c, pc, ic)                                                     \
        {                                                                    \
            const float s = fmaf(-2.0f, (pc), csq[ic]);                      \
            const bool t = (s < bestS) || (s == bestS && (ic) < bestI);      \
            bestS = t ? s : bestS; bestI = t ? (ic) : bestI; bestC = t ? (c) : bestC; \
        }
        CHECK(1, p1, idx1) CHECK(2, p2, idx2) CHECK(3, p3, idx3)
        CHECK(4, p4, idx4) CHECK(5, p5, idx5) CHECK(6, p6, idx6) CHECK(7, p7, idx7)
#undef CHECK

        const int bI = __builtin_amdgcn_readlane(bestI, 63);
        const int bC = __builtin_amdgcn_readlane(bestC, 63);

        if (lane == 0) outIdx[row] = (float)bI;

        float4 q4 = cv0;
        if (bC == 1) q4 = cv1;
        if (bC == 2) q4 = cv2;
        if (bC == 3) q4 = cv3;
        if (bC == 4) q4 = cv4;
        if (bC == 5) q4 = cv5;
        if (bC == 6) q4 = cv6;
        if (bC == 7) q4 = cv7;
        *reinterpret_cast<float4*>(zq + (size_t)row * DDIM + lane * 4) = q4;
    }
}

extern "C" void kernel_launch(void* const* d_in, const int* in_sizes, int n_in,
                              void* d_out, int out_size, void* d_ws, size_t ws_size,
                              hipStream_t stream) {
    const float* z  = (const float*)d_in[0];   // [16384,256]
    const float* cb = (const float*)d_in[1];   // [1024,256]
    float* out    = (float*)d_out;
    float* zq     = out;                            // 16.77 MB
    float* outIdx = out + (size_t)M_ROWS * DDIM;    // 64 KB

    char* ws = (char*)d_ws;
    _Float16* chp = (_Float16*)ws;                  // 512 KB
    float* csq    = (float*)(ws + 512 * 1024);      // 4 KB

    vq_prep_cb<<<384, 256, 0, stream>>>(cb, chp, csq);
    vq_fused<<<M_ROWS / 64, 512, 0, stream>>>(z, chp, cb, csq, zq, outIdx);
}